// Round 1
// 414.206 us; speedup vs baseline: 1.0220x; 1.0220x over previous
//
#include <hip/hip_runtime.h>
#include <cmath>

#define D 160
#define DD (D*D)          // 25600
#define NVOX (D*D*D)
#define BIGV (NVOX + 2)
#define NBINS 4096
#define HALF 16
#define RGRID 800         // rotate-pass blocks = DD/32, also hist partial count
#define SGRID 1000        // sweep blocks (512 thr, 8 cells/thread)
#define NSWEEP 16

// ---------------------------------------------------------------------------
// Rotate-pipeline box filter (window 32, 'same'), INT packed path.
// Buffer layout (a,b,c) c-contiguous; filter along c; write out[c*DD+a*D+b]
// -> layout (c,a,b). Three passes return to identity with each axis filtered.
// MODE 0 packs classes from raw data (lab init no longer materialized —
// sweep 1 classifies data directly). cw0 low 16 bits, cw1 high 16.
// ---------------------------------------------------------------------------
template<int MODE>
__global__ __launch_bounds__(256) void box_rot_int_kernel(
    const void* __restrict__ vin, unsigned* __restrict__ out)
{
    __shared__ unsigned tin[32][161];
    __shared__ unsigned filt[160][33];
    int L0 = blockIdx.x * 32;
    size_t base = (size_t)L0 * D;

    if (MODE == 0) {
        const float4* s4 = (const float4*)((const float*)vin + base);
        for (int i = threadIdx.x; i < 32 * (D / 4); i += 256) {
            float4 v = s4[i];
            int e = i * 4, r = e / D, c = e - r * D;
            float rr;
            rr = rintf(v.x); tin[r][c]   = (rr==0.f) | ((rr==1.f)?0x10000u:0u);
            rr = rintf(v.y); tin[r][c+1] = (rr==0.f) | ((rr==1.f)?0x10000u:0u);
            rr = rintf(v.z); tin[r][c+2] = (rr==0.f) | ((rr==1.f)?0x10000u:0u);
            rr = rintf(v.w); tin[r][c+3] = (rr==0.f) | ((rr==1.f)?0x10000u:0u);
        }
    } else {
        const uint4* s4 = (const uint4*)((const unsigned*)vin + base);
        for (int i = threadIdx.x; i < 32 * (D / 4); i += 256) {
            uint4 v = s4[i];
            int e = i * 4, r = e / D, c = e - r * D;
            tin[r][c] = v.x; tin[r][c+1] = v.y; tin[r][c+2] = v.z; tin[r][c+3] = v.w;
        }
    }
    __syncthreads();

    {
        int r = threadIdx.x & 31, s = threadIdx.x >> 5;
        int i0 = 20 * s;
        const unsigned* ln = tin[r];
        unsigned sum = 0u;
        int jlo = i0 - 16; if (jlo < 0) jlo = 0;
        int jhi = i0 + 15; if (jhi > D - 1) jhi = D - 1;
        for (int j = jlo; j <= jhi; ++j) sum += ln[j];
        #pragma unroll 4
        for (int k = 0; k < 20; ++k) {
            int i = i0 + k;
            filt[i][r] = sum;
            int add = i + 16, rem = i - 16;
            if (add <= D - 1) sum += ln[add];
            if (rem >= 0)     sum -= ln[rem];
        }
    }
    __syncthreads();

    int r = threadIdx.x & 31;
    for (int c = (threadIdx.x >> 5); c < D; c += 8)
        out[(size_t)c * DD + L0 + r] = filt[c][r];
}

// ---------------------------------------------------------------------------
// Rotate box filter, FLOAT path, pass 1: fuses the lsize*valid gather.
// fp order differs from reference cumsum: perturbs only proba (~1e-7 vs
// 2e-2 threshold); candidates are integer-exact.
// ---------------------------------------------------------------------------
__global__ __launch_bounds__(256) void box_rot_f32_g_kernel(
    const int* __restrict__ lab, const int* __restrict__ cnt,
    const unsigned* __restrict__ cwp, float* __restrict__ out)
{
    __shared__ float tin[32][161];
    __shared__ float filt[160][33];
    int L0 = blockIdx.x * 32;
    size_t base = (size_t)L0 * D;

    const int4*  lab4 = (const int4*)(lab + base);
    const uint4* cw4  = (const uint4*)(cwp + base);
    for (int i = threadIdx.x; i < 32 * (D / 4); i += 256) {
        int4 l = lab4[i];
        uint4 cw = cw4[i];
        int e = i * 4, r = e / D, c = e - r * D;
        tin[r][c]   = (l.x != BIGV && (cw.x >> 16) > 100u) ? (float)cnt[l.x] : 0.f;
        tin[r][c+1] = (l.y != BIGV && (cw.y >> 16) > 100u) ? (float)cnt[l.y] : 0.f;
        tin[r][c+2] = (l.z != BIGV && (cw.z >> 16) > 100u) ? (float)cnt[l.z] : 0.f;
        tin[r][c+3] = (l.w != BIGV && (cw.w >> 16) > 100u) ? (float)cnt[l.w] : 0.f;
    }
    __syncthreads();

    {
        int r = threadIdx.x & 31, s = threadIdx.x >> 5;
        int i0 = 20 * s;
        const float* ln = tin[r];
        float sum = 0.f;
        int jlo = i0 - 16; if (jlo < 0) jlo = 0;
        int jhi = i0 + 15; if (jhi > D - 1) jhi = D - 1;
        for (int j = jlo; j <= jhi; ++j) sum += ln[j];
        #pragma unroll 4
        for (int k = 0; k < 20; ++k) {
            int i = i0 + k;
            filt[i][r] = sum;
            int add = i + 16, rem = i - 16;
            if (add <= D - 1) sum += ln[add];
            if (rem >= 0)     sum -= ln[rem];
        }
    }
    __syncthreads();

    int r = threadIdx.x & 31;
    for (int c = (threadIdx.x >> 5); c < D; c += 8)
        out[(size_t)c * DD + L0 + r] = filt[c][r];
}

// plain float middle pass
__global__ __launch_bounds__(256) void box_rot_f32_kernel(
    const float* __restrict__ fin, float* __restrict__ out)
{
    __shared__ float tin[32][161];
    __shared__ float filt[160][33];
    int L0 = blockIdx.x * 32;
    size_t base = (size_t)L0 * D;

    const float4* s4 = (const float4*)(fin + base);
    for (int i = threadIdx.x; i < 32 * (D / 4); i += 256) {
        float4 v = s4[i];
        int e = i * 4, r = e / D, c = e - r * D;
        tin[r][c] = v.x; tin[r][c+1] = v.y; tin[r][c+2] = v.z; tin[r][c+3] = v.w;
    }
    __syncthreads();

    {
        int r = threadIdx.x & 31, s = threadIdx.x >> 5;
        int i0 = 20 * s;
        const float* ln = tin[r];
        float sum = 0.f;
        int jlo = i0 - 16; if (jlo < 0) jlo = 0;
        int jhi = i0 + 15; if (jhi > D - 1) jhi = D - 1;
        for (int j = jlo; j <= jhi; ++j) sum += ln[j];
        #pragma unroll 4
        for (int k = 0; k < 20; ++k) {
            int i = i0 + k;
            filt[i][r] = sum;
            int add = i + 16, rem = i - 16;
            if (add <= D - 1) sum += ln[add];
            if (rem >= 0)     sum -= ln[rem];
        }
    }
    __syncthreads();

    int r = threadIdx.x & 31;
    for (int c = (threadIdx.x >> 5); c < D; c += 8)
        out[(size_t)c * DD + L0 + r] = filt[c][r];
}

// ---------------------------------------------------------------------------
// cs pass 3 fused with finalize: filter along x; compute candidates / bin
// idx / LDS histogram directly (cs never materialized).
// Input layout (y,z,x): line L = y*D+z, elems along x. Output p = x*DD+L.
// ---------------------------------------------------------------------------
__global__ __launch_bounds__(256) void box_rot_fin_kernel(
    const float* __restrict__ fin, const unsigned* __restrict__ cwp,
    float* __restrict__ cand, unsigned short* __restrict__ idxbuf,
    int* __restrict__ partial)
{
    __shared__ float tin[32][161];
    __shared__ float filt[160][33];
    __shared__ int lh[NBINS];
    for (int i = threadIdx.x; i < NBINS; i += 256) lh[i] = 0;

    int L0 = blockIdx.x * 32;
    size_t base = (size_t)L0 * D;
    const float4* s4 = (const float4*)(fin + base);
    for (int i = threadIdx.x; i < 32 * (D / 4); i += 256) {
        float4 v = s4[i];
        int e = i * 4, r = e / D, c = e - r * D;
        tin[r][c] = v.x; tin[r][c+1] = v.y; tin[r][c+2] = v.z; tin[r][c+3] = v.w;
    }
    __syncthreads();

    {
        int r = threadIdx.x & 31, s = threadIdx.x >> 5;
        int i0 = 20 * s;
        const float* ln = tin[r];
        float sum = 0.f;
        int jlo = i0 - 16; if (jlo < 0) jlo = 0;
        int jhi = i0 + 15; if (jhi > D - 1) jhi = D - 1;
        for (int j = jlo; j <= jhi; ++j) sum += ln[j];
        #pragma unroll 4
        for (int k = 0; k < 20; ++k) {
            int i = i0 + k;
            filt[i][r] = sum;
            int add = i + 16, rem = i - 16;
            if (add <= D - 1) sum += ln[add];
            if (rem >= 0)     sum -= ln[rem];
        }
    }
    __syncthreads();

    int r = threadIdx.x & 31;
    int L = L0 + r;
    int y = L / D, z = L - (L / D) * D;
    bool byz = (y >= HALF && y < D - HALF && z >= HALF && z < D - HALF);
    int wy = min(y + 15, D - 1) - max(y - 16, 0) + 1;
    int wz = min(z + 15, D - 1) - max(z - 16, 0) + 1;
    for (int c = (threadIdx.x >> 5); c < D; c += 8) {   // c == x
        int p = c * DD + L;
        unsigned pk = cwp[p];
        unsigned cw0 = pk & 0xFFFFu;
        unsigned cw1 = pk >> 16;
        int wx = min(c + 15, D - 1) - max(c - 16, 0) + 1;
        unsigned cw2 = (unsigned)(wx * wy * wz) - cw0 - cw1;
        float v0 = (cw0 > 100u) ? 1.f : 0.f;
        float v1 = (cw1 > 100u) ? 1.f : 0.f;
        float v2 = (cw2 > 100u) ? 1.f : 0.f;
        float border = (byz && c >= HALF && c < D - HALF) ? 1.f : 0.f;
        float cd = (border * v1 + v0 + v2 >= 2.f) ? 1.f : 0.f;
        cand[p] = cd;
        float mean = (cw1 > 0u) ? filt[c][r] / fmaxf((float)cw1, 1.f) : 0.f;
        int idx = (int)rintf(cd * mean);    // round half-to-even == jnp.round
        idx = min(max(idx, 0), NBINS - 1);
        idxbuf[p] = (unsigned short)idx;
        if (idx != 0) atomicAdd(&lh[idx], 1);   // hist[0] never consumed
    }
    __syncthreads();
    int* po = partial + blockIdx.x * NBINS;
    for (int i = threadIdx.x; i < NBINS; i += 256) po[i] = lh[i];
}

// ---------------------------------------------------------------------------
// Flat CCL sweeps, one launch per sweep (cheapest generation boundary
// measured: grid.sync ~280us/gen (R8), flag-spin ~270us/gen (R9), LDS halo
// fusion 55us/2gen (R5) — all lose to ~9-12us kernel-launch sync).
// CPT=8 split as TWO CONTIGUOUS HALF-WAVE CHUNKS: lane l owns voxels
// wbase+4l..+4 (chunk A) and wbase+256+4l..+4 (chunk B). Each int4 store
// instruction now covers a contiguous 1KB per wave = 16 fully-dirty lines
// (the previous 32B-strided two-quad pattern half-dirtied every sector per
// instruction -> 3.2x L2 partial-sector writeback amplification: measured
// WRITE_SIZE 51.9MB/sweep vs 16.4MB dst). Neighbor int4 loads also become
// fully contiguous. z-stitching stays in-register: A.lane63's right nbr is
// shfl(cB.x,0); B.lane0's left nbr is shfl(cA.w,63); only wave-edge elems
// load from global.
// XCD swizzle: each XCD owns a contiguous 20-plane x-slab (2 MB, L2-
// resident): verified FETCH 28.9 -> 9.1 MB/sweep.
// Sweep 1 classifies raw data inline (no materialized lab-init buffer).
// ---------------------------------------------------------------------------
__device__ __forceinline__ int min6(int c, int a, int b, int d, int e, int f, int g) {
    if (c == BIGV) return BIGV;
    return min(min(min(c, a), min(b, d)), min(min(e, f), g));
}

__device__ __forceinline__ void wave_count(int l, int lane, int* __restrict__ cnt) {
    unsigned long long remaining = __ballot(l != BIGV);
    while (remaining) {
        int leader = __ffsll((unsigned long long)remaining) - 1;
        int ll = __shfl(l, leader, 64);
        unsigned long long mm = __ballot(l == ll);
        if (lane == leader) atomicAdd(&cnt[ll], (int)__popcll(mm & remaining));
        remaining &= ~mm;
    }
}

__device__ __forceinline__ int4 cls4(float4 v, int p0) {
    int4 l;
    l.x = (rintf(v.x) == 1.f) ? (p0 + 1) : BIGV;
    l.y = (rintf(v.y) == 1.f) ? (p0 + 2) : BIGV;
    l.z = (rintf(v.z) == 1.f) ? (p0 + 3) : BIGV;
    l.w = (rintf(v.w) == 1.f) ? (p0 + 4) : BIGV;
    return l;
}

// per-chunk neighbor gather + min combine (4 voxels contiguous in z)
#define SWEEP_CHUNK(c, lm, rm, q, p, LOAD4, outv)                         \
    {                                                                     \
        int rr = (p) / D;                                                 \
        int yy = rr % D;                                                  \
        int xx = rr / D;                                                  \
        int4 yl = BIG4, yh = BIG4, xl = BIG4, xh = BIG4;                  \
        if (yy > 0)     yl = LOAD4((q) - D/4,  (p) - D);                  \
        if (yy < D - 1) yh = LOAD4((q) + D/4,  (p) + D);                  \
        if (xx > 0)     xl = LOAD4((q) - DD/4, (p) - DD);                 \
        if (xx < D - 1) xh = LOAD4((q) + DD/4, (p) + DD);                 \
        outv.x = min6(c.x, lm,  c.y, yl.x, yh.x, xl.x, xh.x);             \
        outv.y = min6(c.y, c.x, c.z, yl.y, yh.y, xl.y, xh.y);             \
        outv.z = min6(c.z, c.y, c.w, yl.z, yh.z, xl.z, xh.z);             \
        outv.w = min6(c.w, c.z, rm,  yl.w, yh.w, xl.w, xh.w);             \
    }

// sweep 1: gen-1 labels straight from data (lab0 derived, never stored)
__global__ __launch_bounds__(512) void ccl_sweep1_data_kernel(
    const float* __restrict__ data, int* __restrict__ outp)
{
    int b = blockIdx.x;                          // 0..999
    int sb = (b & 7) * (SGRID / 8) + (b >> 3);   // XCD-contiguous x-slab
    int lane = threadIdx.x & 63;
    int wv   = threadIdx.x >> 6;                 // wave in block, 0..7
    int wbase = sb * 4096 + wv * 512;            // wave's first voxel
    int pA = wbase + 4 * lane;
    int pB = pA + 256;
    int qA = pA >> 2, qB = pB >> 2;
    const float4* d4 = (const float4*)data;
    int4 cA = cls4(d4[qA], pA), cB = cls4(d4[qB], pB);

    int zA = pA % D, zB = pB % D;
    int lmA = __shfl_up(cA.w, 1);
    int rmA = __shfl_down(cA.x, 1);
    int lmB = __shfl_up(cB.w, 1);
    int rmB = __shfl_down(cB.x, 1);
    int stA = __shfl(cB.x, 0, 64);   // voxel wbase+256 (A.lane63 right nbr)
    int stB = __shfl(cA.w, 63, 64);  // voxel wbase+255 (B.lane0 left nbr)
    if (lane == 63) rmA = stA;
    if (lane == 0)  lmB = stB;
    if (zA == 0)          lmA = BIGV;
    else if (lane == 0)   lmA = (rintf(data[pA - 1]) == 1.f) ? pA : BIGV;
    if (zA == D - 4)      rmA = BIGV;
    if (zB == 0)          lmB = BIGV;
    if (zB == D - 4)      rmB = BIGV;
    else if (lane == 63)  rmB = (rintf(data[pB + 4]) == 1.f) ? (pB + 5) : BIGV;

    const int4 BIG4 = make_int4(BIGV, BIGV, BIGV, BIGV);
    #define LOADD(qq, pp) cls4(d4[(qq)], (pp))
    int4 oA, oB;
    SWEEP_CHUNK(cA, lmA, rmA, qA, pA, LOADD, oA);
    SWEEP_CHUNK(cB, lmB, rmB, qB, pB, LOADD, oB);
    #undef LOADD

    int4* out4 = (int4*)outp;
    out4[qA] = oA; out4[qB] = oB;
}

template<int COUNT>
__global__ __launch_bounds__(512) void ccl_sweep8_kernel(
    const int* __restrict__ lab, int* __restrict__ outp, int* __restrict__ cnt)
{
    int b = blockIdx.x;                          // 0..999
    int sb = (b & 7) * (SGRID / 8) + (b >> 3);   // XCD-contiguous x-slab
    int lane = threadIdx.x & 63;
    int wv   = threadIdx.x >> 6;                 // wave in block, 0..7
    int wbase = sb * 4096 + wv * 512;            // wave's first voxel
    int pA = wbase + 4 * lane;
    int pB = pA + 256;
    int qA = pA >> 2, qB = pB >> 2;
    const int4* lab4 = (const int4*)lab;
    int4 cA = lab4[qA], cB = lab4[qB];

    int zA = pA % D, zB = pB % D;
    int lmA = __shfl_up(cA.w, 1);
    int rmA = __shfl_down(cA.x, 1);
    int lmB = __shfl_up(cB.w, 1);
    int rmB = __shfl_down(cB.x, 1);
    int stA = __shfl(cB.x, 0, 64);   // voxel wbase+256 (A.lane63 right nbr)
    int stB = __shfl(cA.w, 63, 64);  // voxel wbase+255 (B.lane0 left nbr)
    if (lane == 63) rmA = stA;
    if (lane == 0)  lmB = stB;
    if (zA == 0)          lmA = BIGV;
    else if (lane == 0)   lmA = lab[pA - 1];
    if (zA == D - 4)      rmA = BIGV;
    if (zB == 0)          lmB = BIGV;
    if (zB == D - 4)      rmB = BIGV;
    else if (lane == 63)  rmB = lab[pB + 4];

    const int4 BIG4 = make_int4(BIGV, BIGV, BIGV, BIGV);
    #define LOADL(qq, pp) lab4[(qq)]
    int4 oA, oB;
    SWEEP_CHUNK(cA, lmA, rmA, qA, pA, LOADL, oA);
    SWEEP_CHUNK(cB, lmB, rmB, qB, pB, LOADL, oB);
    #undef LOADL

    int4* out4 = (int4*)outp;
    out4[qA] = oA; out4[qB] = oB;

    if (COUNT) {   // final sweep: component-size count from registers
        wave_count(oA.x, lane, cnt);
        wave_count(oA.y, lane, cnt);
        wave_count(oA.z, lane, cnt);
        wave_count(oA.w, lane, cnt);
        wave_count(oB.x, lane, cnt);
        wave_count(oB.y, lane, cnt);
        wave_count(oB.z, lane, cnt);
        wave_count(oB.w, lane, cnt);
    }
}

// ---------------------------------------------------------------------------
// hist[bin] = sum over RGRID block partials (coalesced, L2-resident)
// ---------------------------------------------------------------------------
__global__ __launch_bounds__(256) void hist_reduce_kernel(
    const int* __restrict__ partial, int* __restrict__ hist)
{
    int bin = blockIdx.x * 256 + threadIdx.x;   // 16 x 256 = 4096
    int s = 0;
    #pragma unroll 4
    for (int b = 0; b < RGRID; ++b) s += partial[b * NBINS + bin];
    hist[bin] = s;
}

// ---------------------------------------------------------------------------
// histogram post-processing: rec -> ph_full (normalized), S = sum hist*ph.
// Guards (sumrec>0, S>0) degrade an all-zero histogram to 0 instead of NaN.
// ---------------------------------------------------------------------------
__global__ __launch_bounds__(256) void hist_post_kernel(
    const int* __restrict__ hist, float* __restrict__ ph_full,
    float* __restrict__ Sout)
{
    __shared__ float red[256];
    int t = threadIdx.x;

    float loc = 0.f;
    for (int b = t; b < NBINS; b += 256)
        if (b >= 1) loc += (float)hist[b];
    red[t] = loc; __syncthreads();
    for (int o = 128; o > 0; o >>= 1) { if (t < o) red[t] += red[t + o]; __syncthreads(); }
    float numb = red[0]; __syncthreads();

    loc = 0.f;
    for (int b = t; b < NBINS; b += 256) {
        float r = 0.f;
        if (b >= 1) {
            int h = hist[b];
            if (h > 0) r = numb / (float)h;
        }
        ph_full[b] = r;
        loc += r;
    }
    red[t] = loc; __syncthreads();
    for (int o = 128; o > 0; o >>= 1) { if (t < o) red[t] += red[t + o]; __syncthreads(); }
    float sumrec = red[0]; __syncthreads();
    float inv_sumrec = (sumrec > 0.f) ? 1.f / sumrec : 0.f;

    loc = 0.f;
    for (int b = t; b < NBINS; b += 256) {
        float ph = (b >= 1) ? ph_full[b] * inv_sumrec : 0.f;
        ph_full[b] = ph;
        loc += ph * (float)hist[b];
    }
    red[t] = loc; __syncthreads();
    for (int o = 128; o > 0; o >>= 1) { if (t < o) red[t] += red[t + o]; __syncthreads(); }
    if (t == 0) Sout[0] = (red[0] > 0.f) ? red[0] : 1.f;
}

__global__ __launch_bounds__(256) void proba_kernel(
    const unsigned short* __restrict__ idxbuf,
    const float* __restrict__ ph_full, const float* __restrict__ Sv,
    float* __restrict__ outp)
{
    int t = blockIdx.x * blockDim.x + threadIdx.x;   // exact grid NVOX/4
    ushort4 i4 = ((const ushort4*)idxbuf)[t];
    float inv = 1.f / Sv[0];
    float4 o;
    o.x = ph_full[i4.x] * inv;
    o.y = ph_full[i4.y] * inv;
    o.z = ph_full[i4.z] * inv;
    o.w = ph_full[i4.w] * inv;
    ((float4*)outp)[t] = o;
}

// ---------------------------------------------------------------------------
extern "C" void kernel_launch(void* const* d_in, const int* in_sizes, int n_in,
                              void* d_out, int out_size, void* d_ws, size_t ws_size,
                              hipStream_t stream)
{
    const float* data = (const float*)d_in[0];
    float* out   = (float*)d_out;
    float* cand  = out;
    float* proba = out + NVOX;

    char* ws = (char*)d_ws;
    const size_t NB = (size_t)NVOX * sizeof(float);
    float* W1 = (float*)(ws);
    float* W2 = (float*)(ws + NB);
    float* W3 = (float*)(ws + 2 * NB);
    int*   cnt  = (int*)(ws + 3 * NB);                 // NVOX+1 ints
    float* ph   = (float*)(ws + 4 * NB + 16);
    int*   hist = (int*)  (ws + 4 * NB + 16 + NBINS * 4);
    float* Sv   = (float*)(ws + 4 * NB + 16 + 2 * NBINS * 4);
    unsigned short* idxbuf = (unsigned short*)cnt;     // cnt dead after cs pass 1
    int* partial = (int*)W2;                           // W2 dead after cs pass 2

    dim3 rb(256), rg(RGRID);               // 800 blocks (rotate passes)
    dim3 sbk(512), sg(SGRID);              // 1000 blocks (sweeps)
    dim3 pb(256), pg(NVOX / 4 / 256);      // 4000 blocks (proba x4)

    hipMemsetAsync(cnt, 0, (NVOX + 1) * sizeof(int), stream);

    // cw packed box sums via rotate pipeline (pass 1 packs classes; the
    // CCL lab-init buffer is no longer materialized)
    box_rot_int_kernel<0><<<rg, rb, 0, stream>>>(data, (unsigned*)W1);
    box_rot_int_kernel<1><<<rg, rb, 0, stream>>>(W1, (unsigned*)W3);
    box_rot_int_kernel<1><<<rg, rb, 0, stream>>>(W3, (unsigned*)W1);
    unsigned* cwp = (unsigned*)W1;         // original layout

    // CCL: sweep 1 from data; sweeps 2..15 ping-pong; sweep 16 fuses the
    // component-size count. gen1->W2; even gens->W3, odd->W2; gen16->W3.
    ccl_sweep1_data_kernel<<<sg, sbk, 0, stream>>>(data, (int*)W2);
    for (int i = 0; i < NSWEEP - 2; ++i) {             // sweeps 2..15
        const int* src = (i & 1) ? (int*)W3 : (int*)W2;
        int*       dst = (i & 1) ? (int*)W2 : (int*)W3;
        ccl_sweep8_kernel<0><<<sg, sbk, 0, stream>>>(src, dst, nullptr);
    }
    ccl_sweep8_kernel<1><<<sg, sbk, 0, stream>>>((int*)W2, (int*)W3, cnt);
    int* lab = (int*)W3;                   // gen-16 labels

    // cs float box sums (pass 1 fuses lsize*valid gather; pass 3 fuses
    // finalize: cand + idx + histogram — cs never materialized)
    box_rot_f32_g_kernel<<<rg, rb, 0, stream>>>(lab, cnt, cwp, W2);
    box_rot_f32_kernel<<<rg, rb, 0, stream>>>(W2, W3);
    box_rot_fin_kernel<<<rg, rb, 0, stream>>>(W3, cwp, cand, idxbuf, partial);

    hist_reduce_kernel<<<dim3(16), dim3(256), 0, stream>>>(partial, hist);
    hist_post_kernel<<<1, 256, 0, stream>>>(hist, ph, Sv);
    proba_kernel<<<pg, pb, 0, stream>>>(idxbuf, ph, Sv, proba);
}